// Round 4
// baseline (2338.166 us; speedup 1.0000x reference)
//
#include <hip/hip_runtime.h>
#include <hip/hip_bf16.h>
#include <math.h>

#define NB 16384

typedef __bf16 bf16x8 __attribute__((ext_vector_type(8)));
typedef float  f32x4  __attribute__((ext_vector_type(4)));

__device__ __forceinline__ float selu_f(float x) {
    const float kScale = 1.0507009873554805f;
    const float kAlphaScale = 1.7580993408473766f;   // scale*alpha
    return x > 0.0f ? kScale * x : kAlphaScale * (__expf(x) - 1.0f);
}

__device__ __forceinline__ unsigned short f2bf(float x) {   // RNE
    unsigned int u = __float_as_uint(x);
    unsigned int r = (u + 0x7FFFu + ((u >> 16) & 1u)) >> 16;
    return (unsigned short)r;
}

// ---------------------------------------------------------------------------
// Kernel W: dec2_w (784x160 fp32) -> bf16 in workspace
// ---------------------------------------------------------------------------
__global__ __launch_bounds__(256) void k_w2bf(
    const float* __restrict__ w, unsigned short* __restrict__ wb)
{
    const int i = blockIdx.x * 256 + threadIdx.x;
    if (i < 784 * 160) wb[i] = f2bf(w[i]);
}

// ---------------------------------------------------------------------------
// Kernel A: conv1(1->10,5x5) + bias + maxpool2 + selu  ->  conv2(10->20,5x5)
//           + bias + maxpool2 + selu  ->  x2[B][320]   (4 images per block)
// Phase-1 patches read from GLOBAL (L1-resident, no sImg) -> LDS 23.2KB ->
// 6 blocks/CU (24 waves/CU). Weights via wave-uniform s_load. Phase-2 patch
// double-buffered in registers.
// ---------------------------------------------------------------------------
#define X1S 1448   // per-image x1 stride (pad +8 floats)

__global__ __launch_bounds__(256, 6) void k_conv_fused(
    const float* __restrict__ images,
    const float* __restrict__ conv1_w, const float* __restrict__ conv1_b,
    const float* __restrict__ conv2_w, const float* __restrict__ conv2_b,
    float* __restrict__ x2)
{
    __shared__ float sX1[4][X1S];

    const int t  = threadIdx.x;
    const int b0 = blockIdx.x * 4;

    // ---- phase 1: conv1 + pool + selu -> sX1[img][c*144 + pos] ----
    // flat loop over 4*144 = 576 (img,pos) items; patch in regs, 10 channels
    // per patch with uniform (scalar) weight loads.
    #pragma unroll
    for (int it = 0; it < 3; ++it) {
        const int item = it * 256 + t;
        if (item < 576) {
            const int img = item / 144;
            const int pos = item - img * 144;
            const int py  = pos / 12;
            const int px  = pos - py * 12;
            float p[36];
            const float* bp = images + (size_t)(b0 + img) * 784 + (2 * py) * 28 + 2 * px;
            #pragma unroll
            for (int r = 0; r < 6; ++r) {
                #pragma unroll
                for (int c2 = 0; c2 < 3; ++c2) {
                    const float2 v = *reinterpret_cast<const float2*>(bp + r * 28 + c2 * 2);
                    p[r * 6 + c2 * 2]     = v.x;
                    p[r * 6 + c2 * 2 + 1] = v.y;
                }
            }
            float* x1 = sX1[img];
            #pragma unroll
            for (int c = 0; c < 10; ++c) {
                const float* w = conv1_w + c * 25;   // uniform -> s_load
                float s0 = 0.f, s1 = 0.f, s2 = 0.f, s3 = 0.f;
                #pragma unroll
                for (int ky = 0; ky < 5; ++ky) {
                    #pragma unroll
                    for (int kx = 0; kx < 5; ++kx) {
                        const float wq = w[ky * 5 + kx];
                        s0 = fmaf(p[ky * 6 + kx],           wq, s0);
                        s1 = fmaf(p[ky * 6 + kx + 1],       wq, s1);
                        s2 = fmaf(p[(ky + 1) * 6 + kx],     wq, s2);
                        s3 = fmaf(p[(ky + 1) * 6 + kx + 1], wq, s3);
                    }
                }
                const float m = fmaxf(fmaxf(s0, s1), fmaxf(s2, s3)) + conv1_b[c];
                x1[c * 144 + pos] = selu_f(m);
            }
        }
    }
    __syncthreads();

    // ---- phase 2: conv2 + pool + selu -> x2[b][oc*16 + pos] ----
    // wave owns 5 output channels; lane = (img, pooled pos). Patch loads
    // double-buffered (pa/pb) so ds_reads overlap the 500-FMA block.
    {
        const int lane = t & 63;
        const int wave = __builtin_amdgcn_readfirstlane(t >> 6);
        const int oc0  = wave * 5;
        const int img  = lane >> 4;
        const int pos  = lane & 15;
        const int py = pos >> 2, px = pos & 3;
        const float* x1 = sX1[img];

        float acc[5][4];
        #pragma unroll
        for (int m = 0; m < 5; ++m) {
            #pragma unroll
            for (int u = 0; u < 4; ++u) acc[m][u] = 0.f;
        }

        float pa[36], pb[36];

#define LOADP(P, ICV)                                                          \
        {                                                                      \
            const float* bp = x1 + (ICV) * 144 + (2 * py) * 12 + 2 * px;       \
            _Pragma("unroll")                                                  \
            for (int r = 0; r < 6; ++r) {                                      \
                _Pragma("unroll")                                              \
                for (int c2 = 0; c2 < 3; ++c2) {                               \
                    const float2 v = *reinterpret_cast<const float2*>(bp + r * 12 + c2 * 2); \
                    P[r * 6 + c2 * 2]     = v.x;                               \
                    P[r * 6 + c2 * 2 + 1] = v.y;                               \
                }                                                              \
            }                                                                  \
        }

#define COMPP(P, ICV)                                                          \
        {                                                                      \
            _Pragma("unroll")                                                  \
            for (int m = 0; m < 5; ++m) {                                      \
                const float* w = conv2_w + ((oc0 + m) * 10 + (ICV)) * 25;      \
                _Pragma("unroll")                                              \
                for (int ky = 0; ky < 5; ++ky) {                               \
                    _Pragma("unroll")                                          \
                    for (int kx = 0; kx < 5; ++kx) {                           \
                        const float wq = w[ky * 5 + kx];                       \
                        acc[m][0] = fmaf(P[ky * 6 + kx],           wq, acc[m][0]); \
                        acc[m][1] = fmaf(P[ky * 6 + kx + 1],       wq, acc[m][1]); \
                        acc[m][2] = fmaf(P[(ky + 1) * 6 + kx],     wq, acc[m][2]); \
                        acc[m][3] = fmaf(P[(ky + 1) * 6 + kx + 1], wq, acc[m][3]); \
                    }                                                          \
                }                                                              \
            }                                                                  \
        }

        LOADP(pa, 0)
        #pragma unroll
        for (int ic = 0; ic < 10; ic += 2) {
            LOADP(pb, ic + 1)
            COMPP(pa, ic)
            if (ic + 2 < 10) LOADP(pa, ic + 2)
            COMPP(pb, ic + 1)
        }
#undef LOADP
#undef COMPP

        float* outp = x2 + (size_t)(b0 + img) * 320;
        #pragma unroll
        for (int m = 0; m < 5; ++m) {
            const int oc = oc0 + m;
            const float v = fmaxf(fmaxf(acc[m][0], acc[m][1]),
                                  fmaxf(acc[m][2], acc[m][3])) + conv2_b[oc];
            outp[oc * 16 + pos] = selu_f(v);
        }
    }
}

// ---------------------------------------------------------------------------
// Kernel B: lin1 (320->50) + selu, lin2 (50->25) -> code   (32 rows/block)
// ---------------------------------------------------------------------------
__global__ __launch_bounds__(256) void k_lin12(
    const float* __restrict__ x2,
    const float* __restrict__ lin1_w, const float* __restrict__ lin1_b,
    const float* __restrict__ lin2_w, const float* __restrict__ lin2_b,
    float* __restrict__ code)
{
    __shared__ float sIn[32][324];
    __shared__ float sH[32][51];
    const int t  = threadIdx.x;
    const int b0 = blockIdx.x * 32;
    {
        const float* g = x2 + (size_t)b0 * 320;
        for (int i = t; i < 32 * 320; i += 256) {
            const int r = i / 320;
            sIn[r][i - r * 320] = g[i];
        }
    }
    __syncthreads();

    for (int idx = t; idx < 1600; idx += 256) {        // 32 x 50
        const int bi = idx & 31;
        const int j  = idx >> 5;
        float s = lin1_b[j];
        const float4* w  = reinterpret_cast<const float4*>(lin1_w + j * 320);
        const float4* xi = reinterpret_cast<const float4*>(&sIn[bi][0]);
        #pragma unroll 4
        for (int k4 = 0; k4 < 80; ++k4) {
            const float4 a = xi[k4];
            const float4 wq = w[k4];
            s = fmaf(a.x, wq.x, s); s = fmaf(a.y, wq.y, s);
            s = fmaf(a.z, wq.z, s); s = fmaf(a.w, wq.w, s);
        }
        sH[bi][j] = selu_f(s);
    }
    __syncthreads();
    for (int idx = t; idx < 800; idx += 256) {         // 32 x 25
        const int bi = idx & 31;
        const int j  = idx >> 5;
        float s = lin2_b[j];
        const float* w = lin2_w + j * 50;
        #pragma unroll
        for (int k = 0; k < 50; ++k) s = fmaf(sH[bi][k], w[k], s);
        code[(size_t)(b0 + bi) * 25 + j] = s;
    }
}

// ---------------------------------------------------------------------------
// Kernel C: per-sample 5x5: A = M*M^T, double Jacobi eigensolver,
//           P = sum of outer products of top-2 eigenvectors -> proj[B][25]
// ---------------------------------------------------------------------------
__global__ __launch_bounds__(64) void k_svdproj(
    const float* __restrict__ code, float* __restrict__ proj)
{
    const int b = blockIdx.x * 64 + threadIdx.x;
    if (b >= NB) return;
    const float* c = code + (size_t)b * 25;

    double M[5][5];
    #pragma unroll
    for (int i = 0; i < 5; ++i) {
        #pragma unroll
        for (int j = 0; j < 5; ++j) M[i][j] = (double)c[i * 5 + j];
    }
    double A[5][5], V[5][5];
    #pragma unroll
    for (int i = 0; i < 5; ++i) {
        #pragma unroll
        for (int j = 0; j < 5; ++j) {
            double s = 0.0;
            #pragma unroll
            for (int k = 0; k < 5; ++k) s += M[i][k] * M[j][k];
            A[i][j] = s;
            V[i][j] = (i == j) ? 1.0 : 0.0;
        }
    }
    for (int sweep = 0; sweep < 8; ++sweep) {
        #pragma unroll
        for (int p = 0; p < 4; ++p) {
            #pragma unroll
            for (int q = p + 1; q < 5; ++q) {
                const double apq = A[p][q];
                if (fabs(apq) > 1e-60) {
                    const double app = A[p][p], aqq = A[q][q];
                    const double tau = (aqq - app) / (2.0 * apq);
                    const double tt  = (tau >= 0.0 ? 1.0 : -1.0) /
                                       (fabs(tau) + sqrt(1.0 + tau * tau));
                    const double cc  = 1.0 / sqrt(1.0 + tt * tt);
                    const double ss  = tt * cc;
                    #pragma unroll
                    for (int i = 0; i < 5; ++i) {
                        if (i == p || i == q) continue;
                        const double aip = A[i][p], aiq = A[i][q];
                        A[i][p] = A[p][i] = cc * aip - ss * aiq;
                        A[i][q] = A[q][i] = ss * aip + cc * aiq;
                    }
                    A[p][p] = app - tt * apq;
                    A[q][q] = aqq + tt * apq;
                    A[p][q] = A[q][p] = 0.0;
                    #pragma unroll
                    for (int i = 0; i < 5; ++i) {
                        const double vip = V[i][p], viq = V[i][q];
                        V[i][p] = cc * vip - ss * viq;
                        V[i][q] = ss * vip + cc * viq;
                    }
                }
            }
        }
    }
    double d[5];
    #pragma unroll
    for (int i = 0; i < 5; ++i) d[i] = A[i][i];
    double sel[5];
    #pragma unroll
    for (int c1 = 0; c1 < 5; ++c1) {
        int cnt = 0;
        #pragma unroll
        for (int c2 = 0; c2 < 5; ++c2) {
            if (c2 == c1) continue;
            if (d[c2] > d[c1] || (d[c2] == d[c1] && c2 < c1)) ++cnt;
        }
        sel[c1] = (cnt < 2) ? 1.0 : 0.0;
    }
    #pragma unroll
    for (int i = 0; i < 5; ++i) {
        #pragma unroll
        for (int j = 0; j < 5; ++j) {
            double s = 0.0;
            #pragma unroll
            for (int k = 0; k < 5; ++k) s += sel[k] * V[i][k] * V[j][k];
            proj[(size_t)b * 25 + i * 5 + j] = (float)s;
        }
    }
}

// ---------------------------------------------------------------------------
// Kernel D: dec1 (25->160) + selu  ->  bf16 h in LDS  ->  dec2 (160->784)
//           via mfma_f32_16x16x32_bf16 + bias + sigmoid -> out[B][784]
// ---------------------------------------------------------------------------
#define HS 168   // padded h row stride in ushorts

__global__ __launch_bounds__(256) void k_decoder(
    const float* __restrict__ proj,
    const float* __restrict__ dec1_w, const float* __restrict__ dec1_b,
    const unsigned short* __restrict__ dec2_wb, const float* __restrict__ dec2_b,
    float* __restrict__ out)
{
    __shared__ unsigned short sH[32 * HS];
    const int t  = threadIdx.x;
    const int b0 = blockIdx.x * 32;
    const int bi = t & 31;     // sample row owned by this thread (phase 1)
    const int j0 = t >> 5;     // 0..7

    // ---- phase 1: h[bi][j] = selu(dec1), j = j0 + 8*i ----
    float p[25];
    {
        const float* pr = proj + (size_t)(b0 + bi) * 25;
        #pragma unroll
        for (int k = 0; k < 25; ++k) p[k] = pr[k];
    }
    #pragma unroll 4
    for (int i = 0; i < 20; ++i) {
        const int j = j0 + i * 8;
        const float* w = dec1_w + j * 25;
        float s = dec1_b[j];
        #pragma unroll
        for (int k = 0; k < 25; ++k) s = fmaf(p[k], w[k], s);
        sH[bi * HS + j] = f2bf(selu_f(s));
    }
    __syncthreads();

    // ---- phase 2: out[32][784] = sigmoid(h @ W^T + b) via MFMA ----
    const int wv   = t >> 6;      // 0..3
    const int lane = t & 63;
    const int arow = lane & 15;   // A row / B col within tile
    const int kgrp = lane >> 4;   // 0..3

    bf16x8 afr[2][5];             // hoisted A fragments: 2 row-tiles x 5 k-steps
    #pragma unroll
    for (int rt = 0; rt < 2; ++rt)
        #pragma unroll
        for (int ks = 0; ks < 5; ++ks)
            afr[rt][ks] = *reinterpret_cast<const bf16x8*>(
                &sH[(rt * 16 + arow) * HS + ks * 32 + kgrp * 8]);

    for (int ct = wv; ct < 49; ct += 4) {
        const int col = ct * 16 + arow;
        bf16x8 bfr[5];
        const unsigned short* wp = dec2_wb + (size_t)col * 160 + kgrp * 8;
        #pragma unroll
        for (int ks = 0; ks < 5; ++ks)
            bfr[ks] = *reinterpret_cast<const bf16x8*>(wp + ks * 32);

        f32x4 acc0 = {0.f, 0.f, 0.f, 0.f};
        f32x4 acc1 = {0.f, 0.f, 0.f, 0.f};
        #pragma unroll
        for (int ks = 0; ks < 5; ++ks) {
            acc0 = __builtin_amdgcn_mfma_f32_16x16x32_bf16(afr[0][ks], bfr[ks], acc0, 0, 0, 0);
            acc1 = __builtin_amdgcn_mfma_f32_16x16x32_bf16(afr[1][ks], bfr[ks], acc1, 0, 0, 0);
        }
        const float bb = dec2_b[col];
        #pragma unroll
        for (int r = 0; r < 4; ++r) {
            const int row = kgrp * 4 + r;          // D: row=(lane>>4)*4+reg
            const float v0 = acc0[r] + bb;
            const float v1 = acc1[r] + bb;
            out[(size_t)(b0 + row) * 784 + col]      = 1.0f / (1.0f + __expf(-v0));
            out[(size_t)(b0 + 16 + row) * 784 + col] = 1.0f / (1.0f + __expf(-v1));
        }
    }
}

// ---------------------------------------------------------------------------
extern "C" void kernel_launch(void* const* d_in, const int* in_sizes, int n_in,
                              void* d_out, int out_size, void* d_ws, size_t ws_size,
                              hipStream_t stream) {
    const float* images  = (const float*)d_in[0];
    const float* conv1_w = (const float*)d_in[1];
    const float* conv1_b = (const float*)d_in[2];
    const float* conv2_w = (const float*)d_in[3];
    const float* conv2_b = (const float*)d_in[4];
    const float* lin1_w  = (const float*)d_in[5];
    const float* lin1_b  = (const float*)d_in[6];
    const float* lin2_w  = (const float*)d_in[7];
    const float* lin2_b  = (const float*)d_in[8];
    const float* dec1_w  = (const float*)d_in[9];
    const float* dec1_b  = (const float*)d_in[10];
    const float* dec2_w  = (const float*)d_in[11];
    const float* dec2_b  = (const float*)d_in[12];

    float* out_img = (float*)d_out;                    // NB*784 fp32
    float* code    = (float*)d_out + (size_t)NB * 784; // NB*25  fp32

    float* x2   = (float*)d_ws;                          // NB*320 fp32
    float* proj = (float*)d_ws + (size_t)NB * 320;       // NB*25  fp32
    unsigned short* wbf = (unsigned short*)((float*)d_ws + (size_t)NB * 345); // 784*160 bf16

    k_w2bf     <<<490,      256, 0, stream>>>(dec2_w, wbf);
    k_conv_fused<<<NB / 4,  256, 0, stream>>>(images, conv1_w, conv1_b,
                                              conv2_w, conv2_b, x2);
    k_lin12    <<<NB / 32, 256, 0, stream>>>(x2, lin1_w, lin1_b,
                                             lin2_w, lin2_b, code);
    k_svdproj  <<<NB / 64, 64, 0, stream>>>(code, proj);
    k_decoder  <<<NB / 32, 256, 0, stream>>>(proj, dec1_w, dec1_b,
                                             wbf, dec2_b, out_img);
}

// Round 5
// 259.209 us; speedup vs baseline: 9.0204x; 9.0204x over previous
//
#include <hip/hip_runtime.h>
#include <hip/hip_bf16.h>
#include <math.h>

#define NB 16384

typedef __bf16 bf16x8 __attribute__((ext_vector_type(8)));
typedef float  f32x4  __attribute__((ext_vector_type(4)));

__device__ __forceinline__ float selu_f(float x) {
    const float kScale = 1.0507009873554805f;
    const float kAlphaScale = 1.7580993408473766f;   // scale*alpha
    return x > 0.0f ? kScale * x : kAlphaScale * (__expf(x) - 1.0f);
}

__device__ __forceinline__ unsigned short f2bf(float x) {   // RNE
    unsigned int u = __float_as_uint(x);
    unsigned int r = (u + 0x7FFFu + ((u >> 16) & 1u)) >> 16;
    return (unsigned short)r;
}

// ---------------------------------------------------------------------------
// Kernel W: dec2_w (784x160 fp32) -> bf16 in workspace
// ---------------------------------------------------------------------------
__global__ __launch_bounds__(256) void k_w2bf(
    const float* __restrict__ w, unsigned short* __restrict__ wb)
{
    const int i = blockIdx.x * 256 + threadIdx.x;
    if (i < 784 * 160) wb[i] = f2bf(w[i]);
}

// ---------------------------------------------------------------------------
// Kernel A: conv1(1->10,5x5) + bias + maxpool2 + selu  ->  conv2(10->20,5x5)
//           + bias + maxpool2 + selu  ->  x2[B][320]   (4 images per block)
// Phase-1 patches read from GLOBAL (L1/L2-resident, no sImg) -> LDS 23.2KB
// -> 6 blocks/CU at VGPR<=80. launch_bounds(256,4): VGPR cap 128 — do NOT
// raise the 2nd arg; (256,6) capped VGPR at ~85 and spilled pa/pb to scratch
// (r4: FETCH 4.5GB, 10x regression). Weights via wave-uniform s_load.
// ---------------------------------------------------------------------------
#define X1S 1448   // per-image x1 stride (pad +8 floats)

__global__ __launch_bounds__(256, 4) void k_conv_fused(
    const float* __restrict__ images,
    const float* __restrict__ conv1_w, const float* __restrict__ conv1_b,
    const float* __restrict__ conv2_w, const float* __restrict__ conv2_b,
    float* __restrict__ x2)
{
    __shared__ float sX1[4][X1S];

    const int t  = threadIdx.x;
    const int b0 = blockIdx.x * 4;

    // ---- phase 1: conv1 + pool + selu -> sX1[img][c*144 + pos] ----
    // flat loop over 4*144 = 576 (img,pos) items; patch in regs, 10 channels
    // per patch with uniform (scalar) weight loads.
    #pragma unroll
    for (int it = 0; it < 3; ++it) {
        const int item = it * 256 + t;
        if (item < 576) {
            const int img = item / 144;
            const int pos = item - img * 144;
            const int py  = pos / 12;
            const int px  = pos - py * 12;
            float p[36];
            const float* bp = images + (size_t)(b0 + img) * 784 + (2 * py) * 28 + 2 * px;
            #pragma unroll
            for (int r = 0; r < 6; ++r) {
                #pragma unroll
                for (int c2 = 0; c2 < 3; ++c2) {
                    const float2 v = *reinterpret_cast<const float2*>(bp + r * 28 + c2 * 2);
                    p[r * 6 + c2 * 2]     = v.x;
                    p[r * 6 + c2 * 2 + 1] = v.y;
                }
            }
            float* x1 = sX1[img];
            #pragma unroll
            for (int c = 0; c < 10; ++c) {
                const float* w = conv1_w + c * 25;   // uniform -> s_load
                float s0 = 0.f, s1 = 0.f, s2 = 0.f, s3 = 0.f;
                #pragma unroll
                for (int ky = 0; ky < 5; ++ky) {
                    #pragma unroll
                    for (int kx = 0; kx < 5; ++kx) {
                        const float wq = w[ky * 5 + kx];
                        s0 = fmaf(p[ky * 6 + kx],           wq, s0);
                        s1 = fmaf(p[ky * 6 + kx + 1],       wq, s1);
                        s2 = fmaf(p[(ky + 1) * 6 + kx],     wq, s2);
                        s3 = fmaf(p[(ky + 1) * 6 + kx + 1], wq, s3);
                    }
                }
                const float m = fmaxf(fmaxf(s0, s1), fmaxf(s2, s3)) + conv1_b[c];
                x1[c * 144 + pos] = selu_f(m);
            }
        }
    }
    __syncthreads();

    // ---- phase 2: conv2 + pool + selu -> x2[b][oc*16 + pos] ----
    // wave owns 5 output channels (uniform -> scalar weight loads);
    // lane = (img, pooled pos). Single patch buffer (keeps VGPR ~64).
    {
        const int lane = t & 63;
        const int wave = __builtin_amdgcn_readfirstlane(t >> 6);
        const int oc0  = wave * 5;
        const int img  = lane >> 4;
        const int pos  = lane & 15;
        const int py = pos >> 2, px = pos & 3;
        const float* x1 = sX1[img];

        float acc[5][4];
        #pragma unroll
        for (int m = 0; m < 5; ++m) {
            #pragma unroll
            for (int u = 0; u < 4; ++u) acc[m][u] = 0.f;
        }
        #pragma unroll 2
        for (int ic = 0; ic < 10; ++ic) {
            float p[36];
            const float* bp = x1 + ic * 144 + (2 * py) * 12 + 2 * px;
            #pragma unroll
            for (int r = 0; r < 6; ++r) {
                #pragma unroll
                for (int c2 = 0; c2 < 3; ++c2) {
                    const float2 v = *reinterpret_cast<const float2*>(bp + r * 12 + c2 * 2);
                    p[r * 6 + c2 * 2]     = v.x;
                    p[r * 6 + c2 * 2 + 1] = v.y;
                }
            }
            #pragma unroll
            for (int m = 0; m < 5; ++m) {
                const float* w = conv2_w + ((oc0 + m) * 10 + ic) * 25;  // uniform
                #pragma unroll
                for (int ky = 0; ky < 5; ++ky) {
                    #pragma unroll
                    for (int kx = 0; kx < 5; ++kx) {
                        const float wq = w[ky * 5 + kx];
                        acc[m][0] = fmaf(p[ky * 6 + kx],           wq, acc[m][0]);
                        acc[m][1] = fmaf(p[ky * 6 + kx + 1],       wq, acc[m][1]);
                        acc[m][2] = fmaf(p[(ky + 1) * 6 + kx],     wq, acc[m][2]);
                        acc[m][3] = fmaf(p[(ky + 1) * 6 + kx + 1], wq, acc[m][3]);
                    }
                }
            }
        }
        float* outp = x2 + (size_t)(b0 + img) * 320;
        #pragma unroll
        for (int m = 0; m < 5; ++m) {
            const int oc = oc0 + m;
            const float v = fmaxf(fmaxf(acc[m][0], acc[m][1]),
                                  fmaxf(acc[m][2], acc[m][3])) + conv2_b[oc];
            outp[oc * 16 + pos] = selu_f(v);
        }
    }
}

// ---------------------------------------------------------------------------
// Kernel B: lin1 (320->50) + selu, lin2 (50->25) -> code   (32 rows/block)
// ---------------------------------------------------------------------------
__global__ __launch_bounds__(256) void k_lin12(
    const float* __restrict__ x2,
    const float* __restrict__ lin1_w, const float* __restrict__ lin1_b,
    const float* __restrict__ lin2_w, const float* __restrict__ lin2_b,
    float* __restrict__ code)
{
    __shared__ float sIn[32][324];
    __shared__ float sH[32][51];
    const int t  = threadIdx.x;
    const int b0 = blockIdx.x * 32;
    {
        const float* g = x2 + (size_t)b0 * 320;
        for (int i = t; i < 32 * 320; i += 256) {
            const int r = i / 320;
            sIn[r][i - r * 320] = g[i];
        }
    }
    __syncthreads();

    for (int idx = t; idx < 1600; idx += 256) {        // 32 x 50
        const int bi = idx & 31;
        const int j  = idx >> 5;
        float s = lin1_b[j];
        const float4* w  = reinterpret_cast<const float4*>(lin1_w + j * 320);
        const float4* xi = reinterpret_cast<const float4*>(&sIn[bi][0]);
        #pragma unroll 4
        for (int k4 = 0; k4 < 80; ++k4) {
            const float4 a = xi[k4];
            const float4 wq = w[k4];
            s = fmaf(a.x, wq.x, s); s = fmaf(a.y, wq.y, s);
            s = fmaf(a.z, wq.z, s); s = fmaf(a.w, wq.w, s);
        }
        sH[bi][j] = selu_f(s);
    }
    __syncthreads();
    for (int idx = t; idx < 800; idx += 256) {         // 32 x 25
        const int bi = idx & 31;
        const int j  = idx >> 5;
        float s = lin2_b[j];
        const float* w = lin2_w + j * 50;
        #pragma unroll
        for (int k = 0; k < 50; ++k) s = fmaf(sH[bi][k], w[k], s);
        code[(size_t)(b0 + bi) * 25 + j] = s;
    }
}

// ---------------------------------------------------------------------------
// Kernel C: per-sample 5x5: A = M*M^T, double Jacobi eigensolver,
//           P = sum of outer products of top-2 eigenvectors -> proj[B][25]
// ---------------------------------------------------------------------------
__global__ __launch_bounds__(64) void k_svdproj(
    const float* __restrict__ code, float* __restrict__ proj)
{
    const int b = blockIdx.x * 64 + threadIdx.x;
    if (b >= NB) return;
    const float* c = code + (size_t)b * 25;

    double M[5][5];
    #pragma unroll
    for (int i = 0; i < 5; ++i) {
        #pragma unroll
        for (int j = 0; j < 5; ++j) M[i][j] = (double)c[i * 5 + j];
    }
    double A[5][5], V[5][5];
    #pragma unroll
    for (int i = 0; i < 5; ++i) {
        #pragma unroll
        for (int j = 0; j < 5; ++j) {
            double s = 0.0;
            #pragma unroll
            for (int k = 0; k < 5; ++k) s += M[i][k] * M[j][k];
            A[i][j] = s;
            V[i][j] = (i == j) ? 1.0 : 0.0;
        }
    }
    for (int sweep = 0; sweep < 8; ++sweep) {
        #pragma unroll
        for (int p = 0; p < 4; ++p) {
            #pragma unroll
            for (int q = p + 1; q < 5; ++q) {
                const double apq = A[p][q];
                if (fabs(apq) > 1e-60) {
                    const double app = A[p][p], aqq = A[q][q];
                    const double tau = (aqq - app) / (2.0 * apq);
                    const double tt  = (tau >= 0.0 ? 1.0 : -1.0) /
                                       (fabs(tau) + sqrt(1.0 + tau * tau));
                    const double cc  = 1.0 / sqrt(1.0 + tt * tt);
                    const double ss  = tt * cc;
                    #pragma unroll
                    for (int i = 0; i < 5; ++i) {
                        if (i == p || i == q) continue;
                        const double aip = A[i][p], aiq = A[i][q];
                        A[i][p] = A[p][i] = cc * aip - ss * aiq;
                        A[i][q] = A[q][i] = ss * aip + cc * aiq;
                    }
                    A[p][p] = app - tt * apq;
                    A[q][q] = aqq + tt * apq;
                    A[p][q] = A[q][p] = 0.0;
                    #pragma unroll
                    for (int i = 0; i < 5; ++i) {
                        const double vip = V[i][p], viq = V[i][q];
                        V[i][p] = cc * vip - ss * viq;
                        V[i][q] = ss * vip + cc * viq;
                    }
                }
            }
        }
    }
    double d[5];
    #pragma unroll
    for (int i = 0; i < 5; ++i) d[i] = A[i][i];
    double sel[5];
    #pragma unroll
    for (int c1 = 0; c1 < 5; ++c1) {
        int cnt = 0;
        #pragma unroll
        for (int c2 = 0; c2 < 5; ++c2) {
            if (c2 == c1) continue;
            if (d[c2] > d[c1] || (d[c2] == d[c1] && c2 < c1)) ++cnt;
        }
        sel[c1] = (cnt < 2) ? 1.0 : 0.0;
    }
    #pragma unroll
    for (int i = 0; i < 5; ++i) {
        #pragma unroll
        for (int j = 0; j < 5; ++j) {
            double s = 0.0;
            #pragma unroll
            for (int k = 0; k < 5; ++k) s += sel[k] * V[i][k] * V[j][k];
            proj[(size_t)b * 25 + i * 5 + j] = (float)s;
        }
    }
}

// ---------------------------------------------------------------------------
// Kernel D: dec1 (25->160) + selu  ->  bf16 h in LDS  ->  dec2 (160->784)
//           via mfma_f32_16x16x32_bf16 + bias + sigmoid -> out[B][784]
// ---------------------------------------------------------------------------
#define HS 168   // padded h row stride in ushorts

__global__ __launch_bounds__(256) void k_decoder(
    const float* __restrict__ proj,
    const float* __restrict__ dec1_w, const float* __restrict__ dec1_b,
    const unsigned short* __restrict__ dec2_wb, const float* __restrict__ dec2_b,
    float* __restrict__ out)
{
    __shared__ unsigned short sH[32 * HS];
    const int t  = threadIdx.x;
    const int b0 = blockIdx.x * 32;
    const int bi = t & 31;     // sample row owned by this thread (phase 1)
    const int j0 = t >> 5;     // 0..7

    // ---- phase 1: h[bi][j] = selu(dec1), j = j0 + 8*i ----
    float p[25];
    {
        const float* pr = proj + (size_t)(b0 + bi) * 25;
        #pragma unroll
        for (int k = 0; k < 25; ++k) p[k] = pr[k];
    }
    #pragma unroll 4
    for (int i = 0; i < 20; ++i) {
        const int j = j0 + i * 8;
        const float* w = dec1_w + j * 25;
        float s = dec1_b[j];
        #pragma unroll
        for (int k = 0; k < 25; ++k) s = fmaf(p[k], w[k], s);
        sH[bi * HS + j] = f2bf(selu_f(s));
    }
    __syncthreads();

    // ---- phase 2: out[32][784] = sigmoid(h @ W^T + b) via MFMA ----
    const int wv   = t >> 6;      // 0..3
    const int lane = t & 63;
    const int arow = lane & 15;   // A row / B col within tile
    const int kgrp = lane >> 4;   // 0..3

    bf16x8 afr[2][5];             // hoisted A fragments: 2 row-tiles x 5 k-steps
    #pragma unroll
    for (int rt = 0; rt < 2; ++rt)
        #pragma unroll
        for (int ks = 0; ks < 5; ++ks)
            afr[rt][ks] = *reinterpret_cast<const bf16x8*>(
                &sH[(rt * 16 + arow) * HS + ks * 32 + kgrp * 8]);

    for (int ct = wv; ct < 49; ct += 4) {
        const int col = ct * 16 + arow;
        bf16x8 bfr[5];
        const unsigned short* wp = dec2_wb + (size_t)col * 160 + kgrp * 8;
        #pragma unroll
        for (int ks = 0; ks < 5; ++ks)
            bfr[ks] = *reinterpret_cast<const bf16x8*>(wp + ks * 32);

        f32x4 acc0 = {0.f, 0.f, 0.f, 0.f};
        f32x4 acc1 = {0.f, 0.f, 0.f, 0.f};
        #pragma unroll
        for (int ks = 0; ks < 5; ++ks) {
            acc0 = __builtin_amdgcn_mfma_f32_16x16x32_bf16(afr[0][ks], bfr[ks], acc0, 0, 0, 0);
            acc1 = __builtin_amdgcn_mfma_f32_16x16x32_bf16(afr[1][ks], bfr[ks], acc1, 0, 0, 0);
        }
        const float bb = dec2_b[col];
        #pragma unroll
        for (int r = 0; r < 4; ++r) {
            const int row = kgrp * 4 + r;          // D: row=(lane>>4)*4+reg
            const float v0 = acc0[r] + bb;
            const float v1 = acc1[r] + bb;
            out[(size_t)(b0 + row) * 784 + col]      = 1.0f / (1.0f + __expf(-v0));
            out[(size_t)(b0 + 16 + row) * 784 + col] = 1.0f / (1.0f + __expf(-v1));
        }
    }
}

// ---------------------------------------------------------------------------
extern "C" void kernel_launch(void* const* d_in, const int* in_sizes, int n_in,
                              void* d_out, int out_size, void* d_ws, size_t ws_size,
                              hipStream_t stream) {
    const float* images  = (const float*)d_in[0];
    const float* conv1_w = (const float*)d_in[1];
    const float* conv1_b = (const float*)d_in[2];
    const float* conv2_w = (const float*)d_in[3];
    const float* conv2_b = (const float*)d_in[4];
    const float* lin1_w  = (const float*)d_in[5];
    const float* lin1_b  = (const float*)d_in[6];
    const float* lin2_w  = (const float*)d_in[7];
    const float* lin2_b  = (const float*)d_in[8];
    const float* dec1_w  = (const float*)d_in[9];
    const float* dec1_b  = (const float*)d_in[10];
    const float* dec2_w  = (const float*)d_in[11];
    const float* dec2_b  = (const float*)d_in[12];

    float* out_img = (float*)d_out;                    // NB*784 fp32
    float* code    = (float*)d_out + (size_t)NB * 784; // NB*25  fp32

    float* x2   = (float*)d_ws;                          // NB*320 fp32
    float* proj = (float*)d_ws + (size_t)NB * 320;       // NB*25  fp32
    unsigned short* wbf = (unsigned short*)((float*)d_ws + (size_t)NB * 345); // 784*160 bf16

    k_w2bf     <<<490,      256, 0, stream>>>(dec2_w, wbf);
    k_conv_fused<<<NB / 4,  256, 0, stream>>>(images, conv1_w, conv1_b,
                                              conv2_w, conv2_b, x2);
    k_lin12    <<<NB / 32, 256, 0, stream>>>(x2, lin1_w, lin1_b,
                                             lin2_w, lin2_b, code);
    k_svdproj  <<<NB / 64, 64, 0, stream>>>(code, proj);
    k_decoder  <<<NB / 32, 256, 0, stream>>>(proj, dec1_w, dec1_b,
                                             wbf, dec2_b, out_img);
}